// Round 1
// baseline (409.781 us; speedup 1.0000x reference)
//
#include <hip/hip_runtime.h>

typedef __bf16 bf16_t;
typedef bf16_t bf16x8 __attribute__((ext_vector_type(8)));
typedef float  floatx4 __attribute__((ext_vector_type(4)));
typedef unsigned int uint;

constexpr int Mdim = 2048;
constexpr int Kdim = 4096;
constexpr int Ndim = 11008;
constexpr int NPK  = Ndim / 8;     // 1376 packed words per k-row
constexpr int BM = 128, BN = 128, BK = 64;
constexpr int SA = 72;             // fused-path As stride (bf16)
constexpr int SB = 72;             // fused-path Bs stride (bf16)
constexpr int SQ = 68;             // qbuf stride (words)

// async global->LDS, 16B per lane, LDS dest = wave-uniform base + lane*16
#define GLOAD_LDS16(g, l) \
    __builtin_amdgcn_global_load_lds((const __attribute__((address_space(1))) void*)(g), \
                                     (__attribute__((address_space(3))) void*)(l), 16, 0, 0)

__global__ void xcast_kernel(const float* __restrict__ x, bf16_t* __restrict__ xb)
{
    const int i = (blockIdx.x * 256 + threadIdx.x) * 8;
    const float4 a = *(const float4*)(x + i);
    const float4 b = *(const float4*)(x + i + 4);
    bf16x8 v;
    v[0] = (bf16_t)a.x; v[1] = (bf16_t)a.y; v[2] = (bf16_t)a.z; v[3] = (bf16_t)a.w;
    v[4] = (bf16_t)b.x; v[5] = (bf16_t)b.y; v[6] = (bf16_t)b.z; v[7] = (bf16_t)b.w;
    *(bf16x8*)(xb + i) = v;
}

// ---------------------------------------------------------------------------
// One-shot W dequant: qweight [k][c] int4-packed -> wt [n][k] bf16 (W^T).
// Same transpose-through-LDS + dequant math as the verified fused kernel,
// just writing the result to HBM once instead of re-doing it per M-tile.
// ---------------------------------------------------------------------------
__global__ __launch_bounds__(256, 4)
void wdeq_kernel(const uint* __restrict__ qweight, const uint* __restrict__ qzeros,
                 const float* __restrict__ scales, bf16_t* __restrict__ wt)
{
    __shared__ uint qbuf[16 * SQ];
    const int t  = threadIdx.x;
    const int n0 = blockIdx.x * 128;   // 86 n-tiles
    const int k0 = blockIdx.y * 64;    // 64 k-tiles
    const int c0 = n0 >> 3;
    const int g  = k0 >> 7;            // quant group (64 | 128)

    // stage 64k x 16c packed words, transposed to qbuf[c][k]
    const int qk  = t >> 2;            // 0..63
    const int qc4 = (t & 3) * 4;
    const uint4 w4 = *(const uint4*)(qweight + (size_t)(k0 + qk) * NPK + c0 + qc4);
    qbuf[(qc4 + 0) * SQ + qk] = w4.x;
    qbuf[(qc4 + 1) * SQ + qk] = w4.y;
    qbuf[(qc4 + 2) * SQ + qk] = w4.z;
    qbuf[(qc4 + 3) * SQ + qk] = w4.w;
    __syncthreads();

    const int nloc  = t & 127;
    const int khalf = t >> 7;
    const int cc    = nloc >> 3;
    const int jsh   = (nloc & 7) * 4;

    const uint  zw = qzeros[(size_t)g * NPK + c0 + cc];
    const float s  = scales[(size_t)g * Ndim + n0 + nloc];
    const float zs = (float)((zw >> jsh) & 15u) * s;
    const uint* qrow = &qbuf[cc * SQ + khalf * 32];
    bf16_t* dst = wt + (size_t)(n0 + nloc) * Kdim + k0 + khalf * 32;
#pragma unroll
    for (int j = 0; j < 4; ++j) {
        const uint4 qa = *(const uint4*)(qrow + j * 8);
        const uint4 qb = *(const uint4*)(qrow + j * 8 + 4);
        bf16x8 v;
        v[0] = (bf16_t)((float)((qa.x >> jsh) & 15u) * s - zs);
        v[1] = (bf16_t)((float)((qa.y >> jsh) & 15u) * s - zs);
        v[2] = (bf16_t)((float)((qa.z >> jsh) & 15u) * s - zs);
        v[3] = (bf16_t)((float)((qa.w >> jsh) & 15u) * s - zs);
        v[4] = (bf16_t)((float)((qb.x >> jsh) & 15u) * s - zs);
        v[5] = (bf16_t)((float)((qb.y >> jsh) & 15u) * s - zs);
        v[6] = (bf16_t)((float)((qb.z >> jsh) & 15u) * s - zs);
        v[7] = (bf16_t)((float)((qb.w >> jsh) & 15u) * s - zs);
        *(bf16x8*)(dst + j * 8) = v;
    }
}

// ---------------------------------------------------------------------------
// Plain bf16 GEMM, m97 structure: 128x128 tile, BK=64, 4 waves, linear LDS,
// global_load_lds width-16 for B (and A when xb is available), 2 barriers/K.
// PREX: A comes pre-converted from xb; else convert fp32 x in-kernel.
// ---------------------------------------------------------------------------
template <bool PREX>
__global__ __launch_bounds__(256, 4)
void gemm_kernel(const float* __restrict__ x, const bf16_t* __restrict__ xb,
                 const bf16_t* __restrict__ wt, const float* __restrict__ bias,
                 float* __restrict__ out)
{
    constexpr int SAg = PREX ? 64 : 72;          // linear when gload_lds, padded when ds_write
    __shared__ bf16_t As[128 * SAg];
    __shared__ bf16_t Bs[128 * 64];              // linear [n][k]

    const int t    = threadIdx.x;
    const int m0   = blockIdx.y * BM;
    const int n0   = blockIdx.x * BN;
    const int wave = t >> 6;
    const int lane = t & 63;
    const int quad = lane >> 4;
    const int l16  = lane & 15;
    const int mw = (wave >> 1) * 64;
    const int nw = (wave & 1) * 64;

    floatx4 acc[4][4];
#pragma unroll
    for (int i = 0; i < 4; ++i)
#pragma unroll
        for (int j = 0; j < 4; ++j)
            acc[i][j] = (floatx4){0.f, 0.f, 0.f, 0.f};

    const int am = t >> 3;          // !PREX staging: row within 32-row chunk
    const int ao = t & 7;           // k-octet
    const int lr = lane >> 3;       // gload row-in-chunk 0..7
    const int lo = (lane & 7) * 8;  // gload k-offset (elements)

    for (int kt = 0; kt < Kdim / BK; ++kt) {
        const int k0 = kt * BK;

        if (PREX) {
#pragma unroll
            for (int p = 0; p < 4; ++p) {
                const int q = wave * 4 + p;     // chunk 0..15 = rows 8q..8q+7
                GLOAD_LDS16(xb + (size_t)(m0 + q * 8 + lr) * Kdim + k0 + lo,
                            As + q * 512);
            }
        } else {
#pragma unroll
            for (int p = 0; p < 4; ++p) {
                const int m = p * 32 + am;
                const float* src = x + (size_t)(m0 + m) * Kdim + k0 + ao * 8;
                const float4 a = *(const float4*)src;
                const float4 b = *(const float4*)(src + 4);
                bf16x8 v;
                v[0] = (bf16_t)a.x; v[1] = (bf16_t)a.y; v[2] = (bf16_t)a.z; v[3] = (bf16_t)a.w;
                v[4] = (bf16_t)b.x; v[5] = (bf16_t)b.y; v[6] = (bf16_t)b.z; v[7] = (bf16_t)b.w;
                *(bf16x8*)&As[m * SAg + ao * 8] = v;
            }
        }
#pragma unroll
        for (int p = 0; p < 4; ++p) {
            const int q = wave * 4 + p;
            GLOAD_LDS16(wt + (size_t)(n0 + q * 8 + lr) * Kdim + k0 + lo,
                        Bs + q * 512);
        }
        __syncthreads();

#pragma unroll
        for (int s = 0; s < 2; ++s) {
            bf16x8 fa[4], fb[4];
#pragma unroll
            for (int mt = 0; mt < 4; ++mt)
                fa[mt] = *(const bf16x8*)&As[(mw + mt * 16 + l16) * SAg + s * 32 + quad * 8];
#pragma unroll
            for (int nt = 0; nt < 4; ++nt)
                fb[nt] = *(const bf16x8*)&Bs[(nw + nt * 16 + l16) * 64 + s * 32 + quad * 8];
#pragma unroll
            for (int mt = 0; mt < 4; ++mt)
#pragma unroll
                for (int nt = 0; nt < 4; ++nt)
                    acc[mt][nt] = __builtin_amdgcn_mfma_f32_16x16x32_bf16(fa[mt], fb[nt], acc[mt][nt], 0, 0, 0);
        }
        __syncthreads();
    }

    // epilogue: row=(quad*4+r), col=l16 per 16x16 tile (verified)
#pragma unroll
    for (int nt = 0; nt < 4; ++nt) {
        const int col = n0 + nw + nt * 16 + l16;
        const float b = bias[col];
#pragma unroll
        for (int mt = 0; mt < 4; ++mt) {
#pragma unroll
            for (int r = 0; r < 4; ++r) {
                const int row = m0 + mw + mt * 16 + quad * 4 + r;
                out[(size_t)row * Ndim + col] = acc[mt][nt][r] + b;
            }
        }
    }
}

// ---------------------------------------------------------------------------
// Fused fallback (previous verified kernel) for small workspace.
// ---------------------------------------------------------------------------
template <bool PRE>
__global__ __launch_bounds__(256, 3)
void qgemm_kernel(const float* __restrict__ x,
                  const bf16_t* __restrict__ xb,
                  const uint* __restrict__ qweight,
                  const uint* __restrict__ qzeros,
                  const float* __restrict__ scales,
                  const float* __restrict__ bias,
                  float* __restrict__ out)
{
    __shared__ bf16_t As[BM * SA];
    __shared__ bf16_t Bs[BN * SB];
    __shared__ uint   qbuf[16 * SQ];

    const int t  = threadIdx.x;
    const int m0 = blockIdx.y * BM;
    const int n0 = blockIdx.x * BN;
    const int c0 = n0 >> 3;

    const int wave = t >> 6;
    const int lane = t & 63;
    const int quad = lane >> 4;
    const int l16  = lane & 15;
    const int mw = (wave >> 1) * 64;
    const int nw = (wave & 1) * 64;

    floatx4 acc[4][4];
#pragma unroll
    for (int i = 0; i < 4; ++i)
#pragma unroll
        for (int j = 0; j < 4; ++j)
            acc[i][j] = (floatx4){0.f, 0.f, 0.f, 0.f};

    const int am = t >> 3;
    const int ao = t & 7;
    const int qk  = t >> 2;
    const int qc4 = (t & 3) * 4;
    const int nloc  = t & 127;
    const int khalf = t >> 7;
    const int cc    = nloc >> 3;
    const int jsh   = (nloc & 7) * 4;

    for (int kt = 0; kt < Kdim / BK; ++kt) {
        const int k0 = kt * BK;
        const int g  = k0 >> 7;

#pragma unroll
        for (int p = 0; p < 4; ++p) {
            const int m = p * 32 + am;
            if (PRE) {
                const bf16x8 v = *(const bf16x8*)(xb + (size_t)(m0 + m) * Kdim + k0 + ao * 8);
                *(bf16x8*)&As[m * SA + ao * 8] = v;
            } else {
                const float* src = x + (size_t)(m0 + m) * Kdim + k0 + ao * 8;
                const float4 a = *(const float4*)src;
                const float4 b = *(const float4*)(src + 4);
                bf16x8 v;
                v[0] = (bf16_t)a.x; v[1] = (bf16_t)a.y; v[2] = (bf16_t)a.z; v[3] = (bf16_t)a.w;
                v[4] = (bf16_t)b.x; v[5] = (bf16_t)b.y; v[6] = (bf16_t)b.z; v[7] = (bf16_t)b.w;
                *(bf16x8*)&As[m * SA + ao * 8] = v;
            }
        }
        {
            const uint4 w4 = *(const uint4*)(qweight + (size_t)(k0 + qk) * NPK + c0 + qc4);
            qbuf[(qc4 + 0) * SQ + qk] = w4.x;
            qbuf[(qc4 + 1) * SQ + qk] = w4.y;
            qbuf[(qc4 + 2) * SQ + qk] = w4.z;
            qbuf[(qc4 + 3) * SQ + qk] = w4.w;
        }
        __syncthreads();

        {
            const uint  zw = qzeros[(size_t)g * NPK + c0 + cc];
            const float s  = scales[(size_t)g * Ndim + n0 + nloc];
            const float zs = (float)((zw >> jsh) & 15u) * s;
            const uint* qrow = &qbuf[cc * SQ + khalf * 32];
#pragma unroll
            for (int j = 0; j < 4; ++j) {
                const uint4 qa = *(const uint4*)(qrow + j * 8);
                const uint4 qb = *(const uint4*)(qrow + j * 8 + 4);
                bf16x8 v;
                v[0] = (bf16_t)((float)((qa.x >> jsh) & 15u) * s - zs);
                v[1] = (bf16_t)((float)((qa.y >> jsh) & 15u) * s - zs);
                v[2] = (bf16_t)((float)((qa.z >> jsh) & 15u) * s - zs);
                v[3] = (bf16_t)((float)((qa.w >> jsh) & 15u) * s - zs);
                v[4] = (bf16_t)((float)((qb.x >> jsh) & 15u) * s - zs);
                v[5] = (bf16_t)((float)((qb.y >> jsh) & 15u) * s - zs);
                v[6] = (bf16_t)((float)((qb.z >> jsh) & 15u) * s - zs);
                v[7] = (bf16_t)((float)((qb.w >> jsh) & 15u) * s - zs);
                *(bf16x8*)&Bs[nloc * SB + khalf * 32 + j * 8] = v;
            }
        }
        __syncthreads();

#pragma unroll
        for (int s = 0; s < 2; ++s) {
            bf16x8 fa[4], fb[4];
#pragma unroll
            for (int mt = 0; mt < 4; ++mt)
                fa[mt] = *(const bf16x8*)&As[(mw + mt * 16 + l16) * SA + s * 32 + quad * 8];
#pragma unroll
            for (int nt = 0; nt < 4; ++nt)
                fb[nt] = *(const bf16x8*)&Bs[(nw + nt * 16 + l16) * SB + s * 32 + quad * 8];
#pragma unroll
            for (int mt = 0; mt < 4; ++mt)
#pragma unroll
                for (int nt = 0; nt < 4; ++nt)
                    acc[mt][nt] = __builtin_amdgcn_mfma_f32_16x16x32_bf16(fa[mt], fb[nt], acc[mt][nt], 0, 0, 0);
        }
        __syncthreads();
    }

#pragma unroll
    for (int nt = 0; nt < 4; ++nt) {
        const int col = n0 + nw + nt * 16 + l16;
        const float b = bias[col];
#pragma unroll
        for (int mt = 0; mt < 4; ++mt) {
#pragma unroll
            for (int r = 0; r < 4; ++r) {
                const int row = m0 + mw + mt * 16 + quad * 4 + r;
                out[(size_t)row * Ndim + col] = acc[mt][nt][r] + b;
            }
        }
    }
}

extern "C" void kernel_launch(void* const* d_in, const int* in_sizes, int n_in,
                              void* d_out, int out_size, void* d_ws, size_t ws_size,
                              hipStream_t stream)
{
    const float* x        = (const float*)d_in[0];
    const uint*  qweight  = (const uint*)d_in[1];
    const uint*  qzeros   = (const uint*)d_in[2];
    const float* scales   = (const float*)d_in[3];
    const float* bias     = (const float*)d_in[4];
    float*       out      = (float*)d_out;

    const size_t wb_bytes = (size_t)Kdim * Ndim * sizeof(bf16_t);   // 90.2 MB (== out size)
    const size_t xb_bytes = (size_t)Mdim * Kdim * sizeof(bf16_t);   // 16.8 MB

    dim3 ggrid(Ndim / BN, Mdim / BM);   // 86 x 16

    if (ws_size >= wb_bytes) {
        // --- pre-dequant path: W dequantized exactly once ---
        bf16_t* wt = (bf16_t*)d_ws;
        wdeq_kernel<<<dim3(Ndim / 128, Kdim / 64), 256, 0, stream>>>(qweight, qzeros, scales, wt);
        if (ws_size >= wb_bytes + xb_bytes) {
            bf16_t* xb = (bf16_t*)((char*)d_ws + wb_bytes);
            xcast_kernel<<<(Mdim * Kdim) / (256 * 8), 256, 0, stream>>>(x, xb);
            gemm_kernel<true><<<ggrid, dim3(256), 0, stream>>>(x, xb, wt, bias, out);
        } else {
            gemm_kernel<false><<<ggrid, dim3(256), 0, stream>>>(x, nullptr, wt, bias, out);
        }
    } else {
        // --- fused fallback (previous verified kernel) ---
        bf16_t* xb = (bf16_t*)d_ws;
        if (ws_size >= xb_bytes) {
            xcast_kernel<<<(Mdim * Kdim) / (256 * 8), 256, 0, stream>>>(x, xb);
            qgemm_kernel<true><<<ggrid, dim3(256), 0, stream>>>(x, xb, qweight, qzeros, scales, bias, out);
        } else {
            qgemm_kernel<false><<<ggrid, dim3(256), 0, stream>>>(x, xb, qweight, qzeros, scales, bias, out);
        }
    }
}

// Round 2
// 394.079 us; speedup vs baseline: 1.0398x; 1.0398x over previous
//
#include <hip/hip_runtime.h>

typedef __bf16 bf16_t;
typedef bf16_t bf16x8 __attribute__((ext_vector_type(8)));
typedef float  floatx4 __attribute__((ext_vector_type(4)));
typedef unsigned int uint;

constexpr int Mdim = 2048;
constexpr int Kdim = 4096;
constexpr int Ndim = 11008;
constexpr int NPK  = Ndim / 8;     // 1376 packed words per k-row
constexpr int SQ   = 68;           // qbuf stride (words)
// fused-fallback tile params
constexpr int BM = 128, BN = 128, BK = 64;
constexpr int SA = 72, SB = 72;

#define GLOAD_LDS16(g, l) \
    __builtin_amdgcn_global_load_lds((const __attribute__((address_space(1))) void*)(g), \
                                     (__attribute__((address_space(3))) void*)(l), 16, 0, 0)
#define MFMA(a, b, c) __builtin_amdgcn_mfma_f32_16x16x32_bf16((a), (b), (c), 0, 0, 0)
#define BAR()    __builtin_amdgcn_s_barrier()
#define LGKM0()  asm volatile("s_waitcnt lgkmcnt(0)" ::: "memory")
#define LGKM8()  asm volatile("s_waitcnt lgkmcnt(8)" ::: "memory")
#define VMCNT2() asm volatile("s_waitcnt vmcnt(2)" ::: "memory")
#define PRIO1()  __builtin_amdgcn_s_setprio(1)
#define PRIO0()  __builtin_amdgcn_s_setprio(0)

__global__ void xcast_kernel(const float* __restrict__ x, bf16_t* __restrict__ xb)
{
    const int i = (blockIdx.x * 256 + threadIdx.x) * 8;
    const float4 a = *(const float4*)(x + i);
    const float4 b = *(const float4*)(x + i + 4);
    bf16x8 v;
    v[0] = (bf16_t)a.x; v[1] = (bf16_t)a.y; v[2] = (bf16_t)a.z; v[3] = (bf16_t)a.w;
    v[4] = (bf16_t)b.x; v[5] = (bf16_t)b.y; v[6] = (bf16_t)b.z; v[7] = (bf16_t)b.w;
    *(bf16x8*)(xb + i) = v;
}

// ---------------------------------------------------------------------------
// One-shot W dequant: qweight [k][c] int4-packed -> wt [n][k] bf16 (W^T).
// ---------------------------------------------------------------------------
__global__ __launch_bounds__(256, 4)
void wdeq_kernel(const uint* __restrict__ qweight, const uint* __restrict__ qzeros,
                 const float* __restrict__ scales, bf16_t* __restrict__ wt)
{
    __shared__ uint qbuf[16 * SQ];
    const int t  = threadIdx.x;
    const int n0 = blockIdx.x * 128;
    const int k0 = blockIdx.y * 64;
    const int c0 = n0 >> 3;
    const int g  = k0 >> 7;

    const int qk  = t >> 2;
    const int qc4 = (t & 3) * 4;
    const uint4 w4 = *(const uint4*)(qweight + (size_t)(k0 + qk) * NPK + c0 + qc4);
    qbuf[(qc4 + 0) * SQ + qk] = w4.x;
    qbuf[(qc4 + 1) * SQ + qk] = w4.y;
    qbuf[(qc4 + 2) * SQ + qk] = w4.z;
    qbuf[(qc4 + 3) * SQ + qk] = w4.w;
    __syncthreads();

    const int nloc  = t & 127;
    const int khalf = t >> 7;
    const int cc    = nloc >> 3;
    const int jsh   = (nloc & 7) * 4;

    const uint  zw = qzeros[(size_t)g * NPK + c0 + cc];
    const float s  = scales[(size_t)g * Ndim + n0 + nloc];
    const float zs = (float)((zw >> jsh) & 15u) * s;
    const uint* qrow = &qbuf[cc * SQ + khalf * 32];
    bf16_t* dst = wt + (size_t)(n0 + nloc) * Kdim + k0 + khalf * 32;
#pragma unroll
    for (int j = 0; j < 4; ++j) {
        const uint4 qa = *(const uint4*)(qrow + j * 8);
        const uint4 qb = *(const uint4*)(qrow + j * 8 + 4);
        bf16x8 v;
        v[0] = (bf16_t)((float)((qa.x >> jsh) & 15u) * s - zs);
        v[1] = (bf16_t)((float)((qa.y >> jsh) & 15u) * s - zs);
        v[2] = (bf16_t)((float)((qa.z >> jsh) & 15u) * s - zs);
        v[3] = (bf16_t)((float)((qa.w >> jsh) & 15u) * s - zs);
        v[4] = (bf16_t)((float)((qb.x >> jsh) & 15u) * s - zs);
        v[5] = (bf16_t)((float)((qb.y >> jsh) & 15u) * s - zs);
        v[6] = (bf16_t)((float)((qb.z >> jsh) & 15u) * s - zs);
        v[7] = (bf16_t)((float)((qb.w >> jsh) & 15u) * s - zs);
        *(bf16x8*)(dst + j * 8) = v;
    }
}

// ---------------------------------------------------------------------------
// Phased-schedule bf16 GEMM (T1+T2+T3+T4+T5).
// BM=256, BN=128, BK=64. 512 threads = 8 waves (2M x 4N), wave tile 128x32.
// LDS: As[2 buf][2 half][128 r][64 k] = 64 KiB, Bs[2 buf][128 r][64 k] = 32 KiB.
// Swizzle: 16B-block column  blk_lds = blk_global ^ (row & 7)  (both sides:
// inverse-swizzled global source for global_load_lds, swizzled ds_read).
// Iteration = 2 K-tiles, 4 phases x 16 MFMA. Stage slots:
//   ph1: A(2i+1) h0+h1  (region free: read ended prev ph4)
//   ph2: B(2i+2)        (free: read ended ph1)      + vmcnt(2)
//   ph3: A(2i+2) h0+h1  (free: read ended ph2)
//   ph4: B(2i+3)        (free: read ended ph3)      + vmcnt(2)
// vmcnt(2)@ph2 guarantees tile 2i+1 data before ph3/ph4 reads;
// vmcnt(2)@ph4 guarantees tile 2i+2 data before next ph1 reads.
// Tail: stage tile index wraps (T & 63) -> stages garbage into freed regions,
// never read; keeps vmcnt counts uniform (no branches).
// ---------------------------------------------------------------------------
__global__ __launch_bounds__(512, 2)
void gemm8_kernel(const bf16_t* __restrict__ xb, const bf16_t* __restrict__ wt,
                  const float* __restrict__ bias, float* __restrict__ out)
{
    __shared__ bf16_t As[2 * 16384];   // 64 KiB
    __shared__ bf16_t Bs[2 * 8192];    // 32 KiB

    const int t    = threadIdx.x;
    const int w    = t >> 6;
    const int lane = t & 63;
    const int quad = lane >> 4;
    const int l16  = lane & 15;
    const int wm   = w >> 2;           // 0..1  (m half)
    const int wn   = w & 3;            // 0..3  (n quarter)
    const int w64  = w * 64;

    // T1: XCD-aware remap (688 = 8*86, bijective). XCD x <-> m-tile x:
    // its 2 MB xb panel stays L2-resident; W streams through shared L3.
    const int flat = blockIdx.y * 86 + blockIdx.x;
    const int nf   = (flat & 7) * 86 + (flat >> 3);
    const int m0   = (nf / 86) * 256;
    const int n0   = (nf % 86) * 128;

    auto stageA = [&](int T, int h) {
        const int p  = T & 1;
        const int Tk = (T & 63) * 64;
#pragma unroll
        for (int l = 0; l < 2; ++l) {
            const int idx = l * 512 + w64 + lane;
            const int r   = idx >> 3;
            const int bc  = (idx & 7) ^ (r & 7);
            GLOAD_LDS16(xb + (size_t)(m0 + h * 128 + r) * Kdim + Tk + bc * 8,
                        As + (p * 16384 + h * 8192 + (l * 512 + w64) * 8));
        }
    };
    auto stageB = [&](int T) {
        const int p  = T & 1;
        const int Tk = (T & 63) * 64;
#pragma unroll
        for (int l = 0; l < 2; ++l) {
            const int idx = l * 512 + w64 + lane;
            const int r   = idx >> 3;
            const int bc  = (idx & 7) ^ (r & 7);
            GLOAD_LDS16(wt + (size_t)(n0 + r) * Kdim + Tk + bc * 8,
                        Bs + (p * 8192 + (l * 512 + w64) * 8));
        }
    };
    auto lda = [&](int p, int mt, int s) -> bf16x8 {
        const int r = mt * 16 + l16;
        return *(const bf16x8*)(As + p * 16384 + wm * 8192 + r * 64 +
                                ((s * 4 + quad) ^ (l16 & 7)) * 8);
    };
    auto ldb = [&](int p, int nt, int s) -> bf16x8 {
        const int r = wn * 32 + nt * 16 + l16;
        return *(const bf16x8*)(Bs + p * 8192 + r * 64 +
                                ((s * 4 + quad) ^ (l16 & 7)) * 8);
    };

    floatx4 acc[8][2];
#pragma unroll
    for (int i = 0; i < 8; ++i)
#pragma unroll
        for (int j = 0; j < 2; ++j)
            acc[i][j] = (floatx4){0.f, 0.f, 0.f, 0.f};

    // prologue: tile0 A+B, tile1 B; allow tile1's B (newest 2) outstanding
    stageA(0, 0); stageA(0, 1); stageB(0); stageB(1);
    VMCNT2(); BAR();

    bf16x8 av0[4], av1[4], bb[4];

#define MFMA16(MG)                                                         \
    PRIO1();                                                               \
    _Pragma("unroll") for (int mt = 0; mt < 4; ++mt) {                     \
        acc[(MG)*4 + mt][0] = MFMA(av0[mt], bb[0], acc[(MG)*4 + mt][0]);   \
        acc[(MG)*4 + mt][1] = MFMA(av0[mt], bb[1], acc[(MG)*4 + mt][1]);   \
    }                                                                      \
    _Pragma("unroll") for (int mt = 0; mt < 4; ++mt) {                     \
        acc[(MG)*4 + mt][0] = MFMA(av1[mt], bb[2], acc[(MG)*4 + mt][0]);   \
        acc[(MG)*4 + mt][1] = MFMA(av1[mt], bb[3], acc[(MG)*4 + mt][1]);   \
    }                                                                      \
    PRIO0();

    for (int i = 0; i < 32; ++i) {
        // ---- phase 1: buf0, m-frags 0-3 ----
        bb[0] = ldb(0, 0, 0); bb[1] = ldb(0, 1, 0);
        bb[2] = ldb(0, 0, 1); bb[3] = ldb(0, 1, 1);
#pragma unroll
        for (int mt = 0; mt < 4; ++mt) { av0[mt] = lda(0, mt, 0); av1[mt] = lda(0, mt, 1); }
        stageA(2 * i + 1, 0); stageA(2 * i + 1, 1);
        LGKM8();
        BAR(); LGKM0();
        MFMA16(0);
        BAR();

        // ---- phase 2: buf0, m-frags 4-7 ----
#pragma unroll
        for (int mt = 0; mt < 4; ++mt) { av0[mt] = lda(0, mt + 4, 0); av1[mt] = lda(0, mt + 4, 1); }
        stageB(2 * i + 2);
        VMCNT2();
        BAR(); LGKM0();
        MFMA16(1);
        BAR();

        // ---- phase 3: buf1, m-frags 0-3 ----
        bb[0] = ldb(1, 0, 0); bb[1] = ldb(1, 1, 0);
        bb[2] = ldb(1, 0, 1); bb[3] = ldb(1, 1, 1);
#pragma unroll
        for (int mt = 0; mt < 4; ++mt) { av0[mt] = lda(1, mt, 0); av1[mt] = lda(1, mt, 1); }
        stageA(2 * i + 2, 0); stageA(2 * i + 2, 1);
        LGKM8();
        BAR(); LGKM0();
        MFMA16(0);
        BAR();

        // ---- phase 4: buf1, m-frags 4-7 ----
#pragma unroll
        for (int mt = 0; mt < 4; ++mt) { av0[mt] = lda(1, mt + 4, 0); av1[mt] = lda(1, mt + 4, 1); }
        stageB(2 * i + 3);
        VMCNT2();
        BAR(); LGKM0();
        MFMA16(1);
        BAR();
    }
#undef MFMA16

    // epilogue: row = quad*4+r, col = l16 per 16x16 tile (verified layout)
#pragma unroll
    for (int nt = 0; nt < 2; ++nt) {
        const int col = n0 + wn * 32 + nt * 16 + l16;
        const float bv = bias[col];
#pragma unroll
        for (int mt = 0; mt < 8; ++mt) {
#pragma unroll
            for (int r = 0; r < 4; ++r) {
                const int row = m0 + wm * 128 + mt * 16 + quad * 4 + r;
                out[(size_t)row * Ndim + col] = acc[mt][nt][r] + bv;
            }
        }
    }
}

// ---------------------------------------------------------------------------
// Fused fallback (round-0 verified kernel) for small workspace.
// ---------------------------------------------------------------------------
template <bool PRE>
__global__ __launch_bounds__(256, 3)
void qgemm_kernel(const float* __restrict__ x,
                  const bf16_t* __restrict__ xb,
                  const uint* __restrict__ qweight,
                  const uint* __restrict__ qzeros,
                  const float* __restrict__ scales,
                  const float* __restrict__ bias,
                  float* __restrict__ out)
{
    __shared__ bf16_t As[BM * SA];
    __shared__ bf16_t Bs[BN * SB];
    __shared__ uint   qbuf[16 * SQ];

    const int t  = threadIdx.x;
    const int m0 = blockIdx.y * BM;
    const int n0 = blockIdx.x * BN;
    const int c0 = n0 >> 3;

    const int wave = t >> 6;
    const int lane = t & 63;
    const int quad = lane >> 4;
    const int l16  = lane & 15;
    const int mw = (wave >> 1) * 64;
    const int nw = (wave & 1) * 64;

    floatx4 acc[4][4];
#pragma unroll
    for (int i = 0; i < 4; ++i)
#pragma unroll
        for (int j = 0; j < 4; ++j)
            acc[i][j] = (floatx4){0.f, 0.f, 0.f, 0.f};

    const int am = t >> 3;
    const int ao = t & 7;
    const int qk  = t >> 2;
    const int qc4 = (t & 3) * 4;
    const int nloc  = t & 127;
    const int khalf = t >> 7;
    const int cc    = nloc >> 3;
    const int jsh   = (nloc & 7) * 4;

    for (int kt = 0; kt < Kdim / BK; ++kt) {
        const int k0 = kt * BK;
        const int g  = k0 >> 7;

#pragma unroll
        for (int p = 0; p < 4; ++p) {
            const int m = p * 32 + am;
            if (PRE) {
                const bf16x8 v = *(const bf16x8*)(xb + (size_t)(m0 + m) * Kdim + k0 + ao * 8);
                *(bf16x8*)&As[m * SA + ao * 8] = v;
            } else {
                const float* src = x + (size_t)(m0 + m) * Kdim + k0 + ao * 8;
                const float4 a = *(const float4*)src;
                const float4 b = *(const float4*)(src + 4);
                bf16x8 v;
                v[0] = (bf16_t)a.x; v[1] = (bf16_t)a.y; v[2] = (bf16_t)a.z; v[3] = (bf16_t)a.w;
                v[4] = (bf16_t)b.x; v[5] = (bf16_t)b.y; v[6] = (bf16_t)b.z; v[7] = (bf16_t)b.w;
                *(bf16x8*)&As[m * SA + ao * 8] = v;
            }
        }
        {
            const uint4 w4 = *(const uint4*)(qweight + (size_t)(k0 + qk) * NPK + c0 + qc4);
            qbuf[(qc4 + 0) * SQ + qk] = w4.x;
            qbuf[(qc4 + 1) * SQ + qk] = w4.y;
            qbuf[(qc4 + 2) * SQ + qk] = w4.z;
            qbuf[(qc4 + 3) * SQ + qk] = w4.w;
        }
        __syncthreads();

        {
            const uint  zw = qzeros[(size_t)g * NPK + c0 + cc];
            const float s  = scales[(size_t)g * Ndim + n0 + nloc];
            const float zs = (float)((zw >> jsh) & 15u) * s;
            const uint* qrow = &qbuf[cc * SQ + khalf * 32];
#pragma unroll
            for (int j = 0; j < 4; ++j) {
                const uint4 qa = *(const uint4*)(qrow + j * 8);
                const uint4 qb = *(const uint4*)(qrow + j * 8 + 4);
                bf16x8 v;
                v[0] = (bf16_t)((float)((qa.x >> jsh) & 15u) * s - zs);
                v[1] = (bf16_t)((float)((qa.y >> jsh) & 15u) * s - zs);
                v[2] = (bf16_t)((float)((qa.z >> jsh) & 15u) * s - zs);
                v[3] = (bf16_t)((float)((qa.w >> jsh) & 15u) * s - zs);
                v[4] = (bf16_t)((float)((qb.x >> jsh) & 15u) * s - zs);
                v[5] = (bf16_t)((float)((qb.y >> jsh) & 15u) * s - zs);
                v[6] = (bf16_t)((float)((qb.z >> jsh) & 15u) * s - zs);
                v[7] = (bf16_t)((float)((qb.w >> jsh) & 15u) * s - zs);
                *(bf16x8*)&Bs[nloc * SB + khalf * 32 + j * 8] = v;
            }
        }
        __syncthreads();

#pragma unroll
        for (int s = 0; s < 2; ++s) {
            bf16x8 fa[4], fb[4];
#pragma unroll
            for (int mt = 0; mt < 4; ++mt)
                fa[mt] = *(const bf16x8*)&As[(mw + mt * 16 + l16) * SA + s * 32 + quad * 8];
#pragma unroll
            for (int nt = 0; nt < 4; ++nt)
                fb[nt] = *(const bf16x8*)&Bs[(nw + nt * 16 + l16) * SB + s * 32 + quad * 8];
#pragma unroll
            for (int mt = 0; mt < 4; ++mt)
#pragma unroll
                for (int nt = 0; nt < 4; ++nt)
                    acc[mt][nt] = MFMA(fa[mt], fb[nt], acc[mt][nt]);
        }
        __syncthreads();
    }

#pragma unroll
    for (int nt = 0; nt < 4; ++nt) {
        const int col = n0 + nw + nt * 16 + l16;
        const float b = bias[col];
#pragma unroll
        for (int mt = 0; mt < 4; ++mt) {
#pragma unroll
            for (int r = 0; r < 4; ++r) {
                const int row = m0 + mw + mt * 16 + quad * 4 + r;
                out[(size_t)row * Ndim + col] = acc[mt][nt][r] + b;
            }
        }
    }
}

extern "C" void kernel_launch(void* const* d_in, const int* in_sizes, int n_in,
                              void* d_out, int out_size, void* d_ws, size_t ws_size,
                              hipStream_t stream)
{
    const float* x        = (const float*)d_in[0];
    const uint*  qweight  = (const uint*)d_in[1];
    const uint*  qzeros   = (const uint*)d_in[2];
    const float* scales   = (const float*)d_in[3];
    const float* bias     = (const float*)d_in[4];
    float*       out      = (float*)d_out;

    const size_t wb_bytes = (size_t)Kdim * Ndim * sizeof(bf16_t);   // 90.2 MB
    const size_t xb_bytes = (size_t)Mdim * Kdim * sizeof(bf16_t);   // 16.8 MB

    if (ws_size >= wb_bytes + xb_bytes) {
        // pre-dequant + phased GEMM path
        bf16_t* wt = (bf16_t*)d_ws;
        bf16_t* xbuf = (bf16_t*)((char*)d_ws + wb_bytes);
        wdeq_kernel<<<dim3(Ndim / 128, Kdim / 64), 256, 0, stream>>>(qweight, qzeros, scales, wt);
        xcast_kernel<<<(Mdim * Kdim) / (256 * 8), 256, 0, stream>>>(x, xbuf);
        gemm8_kernel<<<dim3(86, 8), dim3(512), 0, stream>>>(xbuf, wt, bias, out);
    } else {
        // fused fallback
        bf16_t* xbuf = (bf16_t*)d_ws;
        dim3 ggrid(Ndim / BN, Mdim / BM);
        if (ws_size >= xb_bytes) {
            xcast_kernel<<<(Mdim * Kdim) / (256 * 8), 256, 0, stream>>>(x, xbuf);
            qgemm_kernel<true><<<ggrid, dim3(256), 0, stream>>>(x, xbuf, qweight, qzeros, scales, bias, out);
        } else {
            qgemm_kernel<false><<<ggrid, dim3(256), 0, stream>>>(x, xbuf, qweight, qzeros, scales, bias, out);
        }
    }
}